// Round 1
// 1378.176 us; speedup vs baseline: 3.1301x; 3.1301x over previous
//
#include <hip/hip_runtime.h>

#define NROWS_TOTAL 65536
#define DDIM 512
#define KCODES 1024
#define LLEV 4
#define ROWS 32
#define KT 512
#define CODES_OFF ((size_t)NROWS_TOTAL * DDIM)
#define MARGIN 0.0625f

typedef __attribute__((address_space(1))) const unsigned int glb_u32_t;
typedef __attribute__((address_space(3))) unsigned int lds_u32_t;
typedef __attribute__((ext_vector_type(8))) short bf16x8;
typedef __attribute__((ext_vector_type(4))) float f32x4;

__device__ __forceinline__ void gload_lds16(const void* g, void* l) {
  __builtin_amdgcn_global_load_lds((glb_u32_t*)g, (lds_u32_t*)l, 16, 0, 0);
}

__device__ __forceinline__ unsigned short f2bf(float f) {
  union { float f; unsigned u; } c; c.f = f;
  return (unsigned short)((c.u + 0x7fffu + ((c.u >> 16) & 1u)) >> 16);
}
__device__ __forceinline__ float bf2f(short h) {
  union { unsigned u; float f; } c; c.u = ((unsigned)(unsigned short)h) << 16;
  return c.f;
}
__device__ __forceinline__ bf16x8 packbf8(float4 a, float4 b) {
  bf16x8 r;
  r[0] = (short)f2bf(a.x); r[1] = (short)f2bf(a.y);
  r[2] = (short)f2bf(a.z); r[3] = (short)f2bf(a.w);
  r[4] = (short)f2bf(b.x); r[5] = (short)f2bf(b.y);
  r[6] = (short)f2bf(b.z); r[7] = (short)f2bf(b.w);
  return r;
}

// ---------------- codebook squared norms (unchanged) ----------------
__global__ void csq_kernel(const float* __restrict__ cb, float* __restrict__ csq) {
  int row  = blockIdx.x * 4 + (threadIdx.x >> 6);
  int lane = threadIdx.x & 63;
  const float* p = cb + (size_t)row * DDIM;
  float s = 0.f;
#pragma unroll
  for (int i = 0; i < 8; ++i) { float v = p[lane + 64 * i]; s = fmaf(v, v, s); }
#pragma unroll
  for (int off = 32; off > 0; off >>= 1) s += __shfl_down(s, off, 64);
  if (lane == 0) csq[row] = s;
}

// ---------------- pack codebook into bf16 B-fragment layout ----------------
// cbB[l][ks][cg16][g][c][j] = bf16(cb[l][cg16*16+c][ks*32 + g*8 + j])
// One B-frag (16 codes x 32 d-slice) is read as a single ds_read_b128/lane:
// lane l (g=l>>4, c=l&15) reads 8 contiguous bf16 -> conflict-free.
__global__ void pack_kernel(const float* __restrict__ cb, unsigned short* __restrict__ cbB) {
  const int gid = blockIdx.x * 256 + threadIdx.x;
  const int g = gid & 3, ks = (gid >> 2) & 15, c = (gid >> 6) & 1023, l = gid >> 16;
  const float* p = cb + ((size_t)(l * KCODES + c)) * DDIM + ks * 32 + g * 8;
  float4 v0 = *(const float4*)p, v1 = *(const float4*)(p + 4);
  bf16x8 r = packbf8(v0, v1);
  *(bf16x8*)(cbB + ((((size_t)(l * 16 + ks) * 64 + (c >> 4)) * 4 + g) * 16 + (c & 15)) * 8) = r;
}

// ---------------- MFMA fast path ----------------
// 1024 blocks x 256 thr (4 waves). 64 rows/block; wave w owns rows w*16..+16,
// all 1024 codes. Distances via mfma_f32_16x16x32_bf16; argmin via
// margin-flag + exact fp32 rescore of near-ties.
__launch_bounds__(256, 2)
__global__ void rq_mfma(const float* __restrict__ x, const float* __restrict__ cb,
                        const float* __restrict__ csq,
                        const unsigned short* __restrict__ cbB,
                        float* __restrict__ out) {
  __shared__ __align__(16) unsigned short ls_b[2][4096];   // 2 x 8 KB DMA chunks
  __shared__ __align__(16) float ls_csq[1024];
  __shared__ unsigned long long ls_flags[64][16];
  __shared__ int ls_mi[64];
  __shared__ int ls_cnt[64];
  __shared__ int ls_hist[LLEV][64];

  const int tid = threadIdx.x;
  const int w = tid >> 6, lane = tid & 63;
  const int g = lane >> 4, c15 = lane & 15;
  const int rowbase = blockIdx.x * 64;
  const int arow_g = rowbase + w * 16 + c15;     // global row for A-fragments

  // ---- prologue: load x -> residual A-frags (bf16, row=lane&15, k=(lane>>4)*8+j)
  bf16x8 areg[16];
#pragma unroll
  for (int ks = 0; ks < 16; ++ks) {
    const float* p = x + (size_t)arow_g * DDIM + ks * 32 + g * 8;
    float4 v0 = *(const float4*)p, v1 = *(const float4*)(p + 4);
    areg[ks] = packbf8(v0, v1);
  }

  auto issue = [&](int lvl, int t, int buf) {
    const int ksn = t & 15, cgn = t >> 4;
    const unsigned short* src = cbB + (size_t)lvl * 524288 + ksn * 32768 + cgn * 4096
                                + w * 1024 + lane * 8;
    unsigned short* dst = &ls_b[buf][w * 1024 + lane * 8];
    gload_lds16(src, dst);
    gload_lds16(src + 512, dst + 512);
  };

  for (int l = 0; l < LLEV; ++l) {
    // stage csq slice for this level
    *(float4*)&ls_csq[tid * 4] = *(const float4*)(csq + l * KCODES + tid * 4);

    float mv[4]; int mi[4]; unsigned long long flg[4];
#pragma unroll
    for (int i = 0; i < 4; ++i) { mv[i] = 3.4e38f; mi[i] = 0; flg[i] = 0ull; }

    if (l == 0) issue(0, 0, 0);   // l>0: chunk0 prefetched at prev level's t=127

    f32x4 acc[8];
    for (int cg = 0; cg < 8; ++cg) {
#pragma unroll
      for (int ks = 0; ks < 16; ++ks) {
        const int buf = ks & 1;
        __syncthreads();                    // chunk t DMA complete; buf^1 free
        const int t = cg * 16 + ks;
        if (t < 127) issue(l, t + 1, buf ^ 1);
        else if (l < LLEV - 1) issue(l + 1, 0, buf ^ 1);

        if (ks == 0) {
#pragma unroll
          for (int f = 0; f < 8; ++f) acc[f] = (f32x4){0.f, 0.f, 0.f, 0.f};
        }
#pragma unroll
        for (int f = 0; f < 8; ++f) {
          bf16x8 bB = *(const bf16x8*)&ls_b[buf][f * 512 + g * 128 + c15 * 8];
          acc[f] = __builtin_amdgcn_mfma_f32_16x16x32_bf16(areg[ks], bB, acc[f], 0, 0, 0);
        }

        if (ks == 15) {
          // epilogue for this 128-code group: q = csq - 2*dot (r_sq common, drops)
          float qv[8][4];
#pragma unroll
          for (int f = 0; f < 8; ++f) {
            float cs = ls_csq[cg * 128 + f * 16 + c15];
#pragma unroll
            for (int i = 0; i < 4; ++i) qv[f][i] = fmaf(-2.0f, acc[f][i], cs);
          }
#pragma unroll
          for (int i = 0; i < 4; ++i) {
            float lv = qv[0][i]; int li = cg * 128 + c15;
#pragma unroll
            for (int f = 1; f < 8; ++f) {
              int code = cg * 128 + f * 16 + c15;
              if (qv[f][i] < lv) { lv = qv[f][i]; li = code; }
            }
#pragma unroll
            for (int off = 1; off < 16; off <<= 1) {
              float ov = __shfl_xor(lv, off, 64);
              int oi = __shfl_xor(li, off, 64);
              if (ov < lv || (ov == lv && oi < li)) { lv = ov; li = oi; }
            }
            if (lv < mv[i] || (lv == mv[i] && li < mi[i])) { mv[i] = lv; mi[i] = li; }
            float thr = mv[i] + MARGIN;
#pragma unroll
            for (int f = 0; f < 8; ++f)
              if (qv[f][i] <= thr) flg[i] |= (1ull << (cg * 8 + f));
          }
        }
      }
    }

    // ---- level end: counts, flags -> LDS ----
    const int row0 = w * 16 + g * 4;
#pragma unroll
    for (int i = 0; i < 4; ++i) {
      int cnt = __popcll(flg[i]);
#pragma unroll
      for (int off = 1; off < 16; off <<= 1) cnt += __shfl_xor(cnt, off, 64);
      ls_flags[row0 + i][c15] = flg[i];
      if (c15 == 0) { ls_mi[row0 + i] = mi[i]; ls_cnt[row0 + i] = cnt; }
    }

    // ---- exact fp32 rescore of near-ties (per wave, own 16 rows) ----
    for (int r = 0; r < 16; ++r) {
      const int row = w * 16 + r;
      if (ls_cnt[row] > 1) {
        const int grow = rowbase + row;
        const float* xp = x + (size_t)grow * DDIM + lane * 8;
        float4 a0 = *(const float4*)xp;
        float4 a1 = *(const float4*)(xp + 4);
        float rs0 = a0.x, rs1 = a0.y, rs2 = a0.z, rs3 = a0.w;
        float rs4 = a1.x, rs5 = a1.y, rs6 = a1.z, rs7 = a1.w;
        for (int lp = 0; lp < l; ++lp) {
          const float* cp = cb + ((size_t)(lp * KCODES + ls_hist[lp][row])) * DDIM + lane * 8;
          float4 e0 = *(const float4*)cp;
          float4 e1 = *(const float4*)(cp + 4);
          rs0 -= e0.x; rs1 -= e0.y; rs2 -= e0.z; rs3 -= e0.w;
          rs4 -= e1.x; rs5 -= e1.y; rs6 -= e1.z; rs7 -= e1.w;
        }
        float pr = 0.f;
        pr = fmaf(rs0, rs0, pr); pr = fmaf(rs1, rs1, pr);
        pr = fmaf(rs2, rs2, pr); pr = fmaf(rs3, rs3, pr);
        pr = fmaf(rs4, rs4, pr); pr = fmaf(rs5, rs5, pr);
        pr = fmaf(rs6, rs6, pr); pr = fmaf(rs7, rs7, pr);
#pragma unroll
        for (int off = 1; off < 64; off <<= 1) pr += __shfl_xor(pr, off, 64);
        float bs = 3.4e38f; int bc = 0x7fffffff;
        for (int j16 = 0; j16 < 16; ++j16) {
          unsigned long long b = ls_flags[row][j16];
          while (b) {
            int bit = __builtin_ctzll(b); b &= b - 1;
            int code = ((bit >> 3) << 7) + ((bit & 7) << 4) + j16;
            const float* cp = cb + ((size_t)(l * KCODES + code)) * DDIM + lane * 8;
            float4 e0 = *(const float4*)cp;
            float4 e1 = *(const float4*)(cp + 4);
            float pd = 0.f;
            pd = fmaf(rs0, e0.x, pd); pd = fmaf(rs1, e0.y, pd);
            pd = fmaf(rs2, e0.z, pd); pd = fmaf(rs3, e0.w, pd);
            pd = fmaf(rs4, e1.x, pd); pd = fmaf(rs5, e1.y, pd);
            pd = fmaf(rs6, e1.z, pd); pd = fmaf(rs7, e1.w, pd);
#pragma unroll
            for (int off = 1; off < 64; off <<= 1) pd += __shfl_xor(pd, off, 64);
            float s = (pr + ls_csq[code]) - 2.0f * pd;
            if (s < bs || (s == bs && code < bc)) { bs = s; bc = code; }
          }
        }
        if (lane == 0) ls_mi[row] = bc;
      }
    }
    __syncthreads();

    // ---- emit codes + history; update residual A-frags ----
    if (tid < 64) {
      int c = ls_mi[tid];
      ls_hist[l][tid] = c;
      out[CODES_OFF + (size_t)(rowbase + tid) * LLEV + l] = (float)c;
    }
    if (l < LLEV - 1) {
      const int idxr = ls_mi[w * 16 + c15];
      const float* crow = cb + ((size_t)(l * KCODES + idxr)) * DDIM;
#pragma unroll
      for (int ks = 0; ks < 16; ++ks) {
        const float* p = crow + ks * 32 + g * 8;
        float4 v0 = *(const float4*)p, v1 = *(const float4*)(p + 4);
        bf16x8 a = areg[ks];
        float4 n0, n1;
        n0.x = bf2f(a[0]) - v0.x; n0.y = bf2f(a[1]) - v0.y;
        n0.z = bf2f(a[2]) - v0.z; n0.w = bf2f(a[3]) - v0.w;
        n1.x = bf2f(a[4]) - v1.x; n1.y = bf2f(a[5]) - v1.y;
        n1.z = bf2f(a[6]) - v1.z; n1.w = bf2f(a[7]) - v1.w;
        areg[ks] = packbf8(n0, n1);
      }
    }
  }

  // ---- quant = ((e0+e1)+e2)+e3, exact reference summation order ----
  __syncthreads();
  {
    const int row = tid >> 2;
    const int d0 = (tid & 3) * 128;
    const float* p0 = cb + ((size_t)(0 * KCODES + ls_hist[0][row])) * DDIM + d0;
    const float* p1 = cb + ((size_t)(1 * KCODES + ls_hist[1][row])) * DDIM + d0;
    const float* p2 = cb + ((size_t)(2 * KCODES + ls_hist[2][row])) * DDIM + d0;
    const float* p3 = cb + ((size_t)(3 * KCODES + ls_hist[3][row])) * DDIM + d0;
    float* op = out + (size_t)(rowbase + row) * DDIM + d0;
#pragma unroll 8
    for (int ch = 0; ch < 32; ++ch) {
      float4 e0 = *(const float4*)(p0 + ch * 4);
      float4 e1 = *(const float4*)(p1 + ch * 4);
      float4 e2 = *(const float4*)(p2 + ch * 4);
      float4 e3 = *(const float4*)(p3 + ch * 4);
      float4 q;
      q.x = ((e0.x + e1.x) + e2.x) + e3.x;
      q.y = ((e0.y + e1.y) + e2.y) + e3.y;
      q.z = ((e0.z + e1.z) + e2.z) + e3.z;
      q.w = ((e0.w + e1.w) + e2.w) + e3.w;
      *(float4*)(op + ch * 4) = q;
    }
  }
}

// ---------------- fallback (fp32, csq-only workspace) ----------------
#define DC 16
#define RSTRIDE 20

__launch_bounds__(256, 2)
__global__ void rq_kernel(const float* __restrict__ x, const float* __restrict__ cb,
                          const float* __restrict__ csq, float* __restrict__ out) {
  __shared__ float ls_cbT[DC * KT];
  __shared__ float ls_r[ROWS * RSTRIDE];
  __shared__ float ls_minv[ROWS * 64];
  __shared__ int   ls_mini[ROWS * 64];
  __shared__ float ls_rsqp[ROWS * 8];
  __shared__ float ls_rsq[ROWS];
  __shared__ int   ls_idx[ROWS];

  const int tid = threadIdx.x;
  const int rg  = tid >> 6;
  const int kg  = tid & 63;
  const int own_row = tid >> 3;
  const int own_d0  = (tid & 7) * 64;
  const int rowbase = blockIdx.x * ROWS;

  float rres[64];
  {
    const float4* xp = (const float4*)(x + (size_t)(rowbase + own_row) * DDIM + own_d0);
#pragma unroll
    for (int i = 0; i < 16; ++i) {
      float4 v = xp[i];
      rres[4*i] = v.x; rres[4*i+1] = v.y; rres[4*i+2] = v.z; rres[4*i+3] = v.w;
    }
  }

  for (int l = 0; l < LLEV; ++l) {
    {
      float p = 0.f;
#pragma unroll
      for (int i = 0; i < 64; ++i) p = fmaf(rres[i], rres[i], p);
      ls_rsqp[own_row * 8 + (tid & 7)] = p;
    }
    __syncthreads();
    if (tid < ROWS) {
      float s = 0.f;
#pragma unroll
      for (int i = 0; i < 8; ++i) s += ls_rsqp[tid * 8 + i];
      ls_rsq[tid] = s;
    }

    float mv[8]; int mi[8];
#pragma unroll
    for (int r = 0; r < 8; ++r) { mv[r] = 3.4e38f; mi[r] = 0; }

    const float* cbl = cb + (size_t)l * KCODES * DDIM;

    for (int kt = 0; kt < KCODES / KT; ++kt) {
      float acc[8][8];
#pragma unroll
      for (int r = 0; r < 8; ++r)
#pragma unroll
        for (int c = 0; c < 8; ++c) acc[r][c] = 0.f;

      for (int dc = 0; dc < DDIM / DC; ++dc) {
        __syncthreads();
        {
          int krow = tid >> 2;
          int dcol = (tid & 3) * 4;
#pragma unroll
          for (int p = 0; p < 8; ++p) {
            int klocal = p * 64 + krow;
            float4 v = *(const float4*)(cbl + (size_t)(kt * KT + klocal) * DDIM + dc * DC + dcol);
            ls_cbT[(dcol + 0) * KT + klocal] = v.x;
            ls_cbT[(dcol + 1) * KT + klocal] = v.y;
            ls_cbT[(dcol + 2) * KT + klocal] = v.z;
            ls_cbT[(dcol + 3) * KT + klocal] = v.w;
          }
        }
        if ((tid & 7) == (dc >> 2)) {
          switch (dc & 3) {
            case 0:
#pragma unroll
              for (int i = 0; i < 4; ++i)
                *(float4*)&ls_r[own_row * RSTRIDE + i * 4] =
                  make_float4(rres[0*16+4*i], rres[0*16+4*i+1], rres[0*16+4*i+2], rres[0*16+4*i+3]);
              break;
            case 1:
#pragma unroll
              for (int i = 0; i < 4; ++i)
                *(float4*)&ls_r[own_row * RSTRIDE + i * 4] =
                  make_float4(rres[1*16+4*i], rres[1*16+4*i+1], rres[1*16+4*i+2], rres[1*16+4*i+3]);
              break;
            case 2:
#pragma unroll
              for (int i = 0; i < 4; ++i)
                *(float4*)&ls_r[own_row * RSTRIDE + i * 4] =
                  make_float4(rres[2*16+4*i], rres[2*16+4*i+1], rres[2*16+4*i+2], rres[2*16+4*i+3]);
              break;
            default:
#pragma unroll
              for (int i = 0; i < 4; ++i)
                *(float4*)&ls_r[own_row * RSTRIDE + i * 4] =
                  make_float4(rres[3*16+4*i], rres[3*16+4*i+1], rres[3*16+4*i+2], rres[3*16+4*i+3]);
              break;
          }
        }
        __syncthreads();
        for (int ds4 = 0; ds4 < DC / 4; ++ds4) {
          float rvf[4][8];
#pragma unroll
          for (int r = 0; r < 8; ++r) {
            float4 t = *(const float4*)&ls_r[(rg * 8 + r) * RSTRIDE + ds4 * 4];
            rvf[0][r] = t.x; rvf[1][r] = t.y; rvf[2][r] = t.z; rvf[3][r] = t.w;
          }
#pragma unroll
          for (int jj = 0; jj < 4; ++jj) {
            float4 cv0 = *(const float4*)&ls_cbT[(ds4 * 4 + jj) * KT + 4 * kg];
            float4 cv1 = *(const float4*)&ls_cbT[(ds4 * 4 + jj) * KT + KT / 2 + 4 * kg];
#pragma unroll
            for (int r = 0; r < 8; ++r) {
              float rv = rvf[jj][r];
              acc[r][0] = fmaf(rv, cv0.x, acc[r][0]);
              acc[r][1] = fmaf(rv, cv0.y, acc[r][1]);
              acc[r][2] = fmaf(rv, cv0.z, acc[r][2]);
              acc[r][3] = fmaf(rv, cv0.w, acc[r][3]);
              acc[r][4] = fmaf(rv, cv1.x, acc[r][4]);
              acc[r][5] = fmaf(rv, cv1.y, acc[r][5]);
              acc[r][6] = fmaf(rv, cv1.z, acc[r][6]);
              acc[r][7] = fmaf(rv, cv1.w, acc[r][7]);
            }
          }
        }
      }
#pragma unroll
      for (int g = 0; g < 2; ++g)
#pragma unroll
        for (int c = 0; c < 4; ++c) {
          int k = kt * KT + g * (KT / 2) + 4 * kg + c;
          float cs = csq[l * KCODES + k];
#pragma unroll
          for (int r = 0; r < 8; ++r) {
            float s = (ls_rsq[rg * 8 + r] + cs) - 2.0f * acc[r][g * 4 + c];
            if (s < mv[r]) { mv[r] = s; mi[r] = k; }
          }
        }
    }

#pragma unroll
    for (int r = 0; r < 8; ++r) {
      ls_minv[(rg * 8 + r) * 64 + kg] = mv[r];
      ls_mini[(rg * 8 + r) * 64 + kg] = mi[r];
    }
    __syncthreads();
    if (tid < ROWS) {
      float bv = ls_minv[tid * 64]; int bi = ls_mini[tid * 64];
      for (int i = 1; i < 64; ++i) {
        float v = ls_minv[tid * 64 + i]; int ii = ls_mini[tid * 64 + i];
        if (v < bv || (v == bv && ii < bi)) { bv = v; bi = ii; }
      }
      ls_idx[tid] = bi;
      out[CODES_OFF + (size_t)(rowbase + tid) * LLEV + l] = (float)bi;
    }
    __syncthreads();
    {
      int idx = ls_idx[own_row];
      const float4* cp = (const float4*)(cbl + (size_t)idx * DDIM + own_d0);
#pragma unroll
      for (int i = 0; i < 16; ++i) {
        float4 v = cp[i];
        rres[4*i]   -= v.x; rres[4*i+1] -= v.y;
        rres[4*i+2] -= v.z; rres[4*i+3] -= v.w;
      }
    }
  }

  {
    const float4* xp = (const float4*)(x + (size_t)(rowbase + own_row) * DDIM + own_d0);
    float4* op = (float4*)(out + (size_t)(rowbase + own_row) * DDIM + own_d0);
#pragma unroll
    for (int i = 0; i < 16; ++i) {
      float4 v = xp[i];
      op[i] = make_float4(v.x - rres[4*i],   v.y - rres[4*i+1],
                          v.z - rres[4*i+2], v.w - rres[4*i+3]);
    }
  }
}

extern "C" void kernel_launch(void* const* d_in, const int* in_sizes, int n_in,
                              void* d_out, int out_size, void* d_ws, size_t ws_size,
                              hipStream_t stream) {
  const float* x  = (const float*)d_in[0];
  const float* cb = (const float*)d_in[1];
  float* out = (float*)d_out;
  float* csq = (float*)d_ws;                                     // [L*K] f32
  unsigned short* cbB = (unsigned short*)((float*)d_ws + 4096);  // [L][16][64][4][16][8] bf16

  const size_t need = 4096 * sizeof(float)
                    + (size_t)LLEV * 16 * 64 * 4 * 16 * 8 * sizeof(unsigned short);

  csq_kernel<<<dim3((LLEV * KCODES) / 4), dim3(256), 0, stream>>>(cb, csq);
  if (ws_size >= need) {
    pack_kernel<<<dim3(1024), dim3(256), 0, stream>>>(cb, cbB);
    rq_mfma<<<dim3(NROWS_TOTAL / 64), dim3(256), 0, stream>>>(x, cb, csq, cbB, out);
  } else {
    rq_kernel<<<dim3(NROWS_TOTAL / ROWS), dim3(256), 0, stream>>>(x, cb, csq, out);
  }
}